// Round 3
// baseline (917.561 us; speedup 1.0000x reference)
//
#include <hip/hip_runtime.h>
#include <math.h>

#define N_NODES 50000
#define N_EDGES 1600000
#define ETOT (N_EDGES + N_NODES)
#define HC 128
#define HEADS 4
#define HID 32
#define NEG_SLOPE 0.2f
#define NPB 32                               // nodes per bucket (aligned)
#define NBUCKETS ((N_NODES + NPB - 1) / NPB) // 1563
#define LOG2E 1.4426950408889634f

// ---------------- CSR build ----------------

__global__ __launch_bounds__(256) void hist_kernel(const int* __restrict__ dstArr, int* __restrict__ deg) {
    int i = blockIdx.x * 256 + threadIdx.x;
    if (i >= ETOT) return;
    int d = (i < N_EDGES) ? dstArr[i] : (i - N_EDGES);
    atomicAdd(&deg[d], 1);
}

__global__ __launch_bounds__(1024) void scanA_kernel(const int* __restrict__ deg,
                                                     int* __restrict__ rowStart, int* __restrict__ blockSum) {
    __shared__ int buf[1024];
    int i = blockIdx.x * 1024 + threadIdx.x;
    int v = (i < N_NODES) ? deg[i] : 0;
    buf[threadIdx.x] = v;
    __syncthreads();
    for (int off = 1; off < 1024; off <<= 1) {
        int t = (threadIdx.x >= off) ? buf[threadIdx.x - off] : 0;
        __syncthreads();
        buf[threadIdx.x] += t;
        __syncthreads();
    }
    if (i < N_NODES) rowStart[i] = buf[threadIdx.x] - v;   // exclusive, pre-offset
    if (threadIdx.x == 1023) blockSum[blockIdx.x] = buf[1023];
}

__global__ void scanB_kernel(const int* __restrict__ blockSum, int* __restrict__ blockOff, int nb) {
    if (threadIdx.x == 0 && blockIdx.x == 0) {
        int acc = 0;
        for (int j = 0; j < nb; j++) { blockOff[j] = acc; acc += blockSum[j]; }
    }
}

__global__ __launch_bounds__(1024) void scanC_kernel(int* __restrict__ rowStart, const int* __restrict__ blockOff) {
    int i = blockIdx.x * 1024 + threadIdx.x;
    if (i < N_NODES) rowStart[i] += blockOff[blockIdx.x];
    if (i == 0) rowStart[N_NODES] = ETOT;   // sentinel: total edges incl. self-loops
}

__global__ __launch_bounds__(256) void init_cursor_kernel(const int* __restrict__ rowStart, int* __restrict__ bucketCursor) {
    int b = blockIdx.x * 256 + threadIdx.x;
    if (b < NBUCKETS) bucketCursor[b] = rowStart[b * NPB];
}

// Pass 1: scatter (src,dst) into bucket-ordered regions (writes hit ~9KB L2 windows)
__global__ __launch_bounds__(256) void bucket_scatter_kernel(const int* __restrict__ srcArr, const int* __restrict__ dstArr,
                                                             int* __restrict__ bucketCursor, int2* __restrict__ E2) {
    int i = blockIdx.x * 256 + threadIdx.x;
    if (i >= ETOT) return;
    int s, d;
    if (i < N_EDGES) { s = srcArr[i]; d = dstArr[i]; }
    else             { s = i - N_EDGES; d = s; }
    int pos = atomicAdd(&bucketCursor[d >> 5], 1);
    E2[pos] = make_int2(s, d);
}

// Pass 2: one block per bucket, LDS cursors, sequential E2 reads, windowed srcS writes
__global__ __launch_bounds__(256) void csr_scatter_kernel(const int2* __restrict__ E2, const int* __restrict__ rowStart,
                                                          int* __restrict__ srcS) {
    __shared__ int lcur[NPB];
    int b = blockIdx.x;
    int n0 = b * NPB;
    int nend = min(n0 + NPB, N_NODES);
    if (threadIdx.x < nend - n0) lcur[threadIdx.x] = rowStart[n0 + threadIdx.x];
    __syncthreads();
    int e0 = rowStart[n0];
    int e1 = rowStart[nend];
    for (int i = e0 + threadIdx.x; i < e1; i += 256) {
        int2 e = E2[i];
        int pos = atomicAdd(&lcur[e.y - n0], 1);
        srcS[pos] = e.x;
    }
}

// ---------------- GEMM: XL = x@Wl + bl, XR = x@Wr + br ----------------

__global__ __launch_bounds__(256) void gemm_kernel(const float* __restrict__ x,
    const float* __restrict__ Wl, const float* __restrict__ bl,
    const float* __restrict__ Wr, const float* __restrict__ br,
    float* __restrict__ XL, float* __restrict__ XR) {
    __shared__ float As[64][68];
    __shared__ float Bs[64][64];
    int t = threadIdx.x;
    int rb = blockIdx.x * 64;
    int cb = blockIdx.y * 64;
    const float* W; const float* bias; float* out; int c0;
    if (cb < HC) { W = Wl; bias = bl; out = XL; c0 = cb; }
    else         { W = Wr; bias = br; out = XR; c0 = cb - HC; }
    int tx = t & 15, ty = t >> 4;
    float acc[4][4];
#pragma unroll
    for (int i = 0; i < 4; i++)
#pragma unroll
        for (int j = 0; j < 4; j++) acc[i][j] = 0.f;

    for (int kt = 0; kt < 2; kt++) {
#pragma unroll
        for (int it = 0; it < 4; it++) {
            int idx = it * 256 + t;
            int r = idx >> 4, f = idx & 15;
            int gr = rb + r;
            float4 v = make_float4(0.f, 0.f, 0.f, 0.f);
            if (gr < N_NODES) v = *reinterpret_cast<const float4*>(&x[gr * HC + kt * 64 + f * 4]);
            *reinterpret_cast<float4*>(&As[r][f * 4]) = v;
        }
#pragma unroll
        for (int it = 0; it < 4; it++) {
            int idx = it * 256 + t;
            int k = idx >> 4, f = idx & 15;
            float4 v = *reinterpret_cast<const float4*>(&W[(kt * 64 + k) * HC + c0 + f * 4]);
            *reinterpret_cast<float4*>(&Bs[k][f * 4]) = v;
        }
        __syncthreads();
#pragma unroll
        for (int k = 0; k < 64; k++) {
            float a0 = As[ty * 4 + 0][k];
            float a1 = As[ty * 4 + 1][k];
            float a2 = As[ty * 4 + 2][k];
            float a3 = As[ty * 4 + 3][k];
            float4 bv = *reinterpret_cast<const float4*>(&Bs[k][tx * 4]);
            acc[0][0] += a0 * bv.x; acc[0][1] += a0 * bv.y; acc[0][2] += a0 * bv.z; acc[0][3] += a0 * bv.w;
            acc[1][0] += a1 * bv.x; acc[1][1] += a1 * bv.y; acc[1][2] += a1 * bv.z; acc[1][3] += a1 * bv.w;
            acc[2][0] += a2 * bv.x; acc[2][1] += a2 * bv.y; acc[2][2] += a2 * bv.z; acc[2][3] += a2 * bv.w;
            acc[3][0] += a3 * bv.x; acc[3][1] += a3 * bv.y; acc[3][2] += a3 * bv.z; acc[3][3] += a3 * bv.w;
        }
        __syncthreads();
    }
    float4 bb = *reinterpret_cast<const float4*>(&bias[c0 + tx * 4]);
#pragma unroll
    for (int i = 0; i < 4; i++) {
        int gr = rb + ty * 4 + i;
        if (gr < N_NODES) {
            float4 o;
            o.x = acc[i][0] + bb.x; o.y = acc[i][1] + bb.y;
            o.z = acc[i][2] + bb.z; o.w = acc[i][3] + bb.w;
            *reinterpret_cast<float4*>(&out[gr * HC + c0 + tx * 4]) = o;
        }
    }
}

// ---------------- Fused GAT: online softmax + weighted aggregate ----------------
// Lane l handles channels 2l,2l+1; head = l>>4. att pre-scaled by log2(e) so
// softmax weights come straight from v_exp_f32 (exp2).

__device__ __forceinline__ float edge_score(float2 xl2, float2 xr2, float2 a2) {
    float hx = xl2.x + xr2.x;
    float hy = xl2.y + xr2.y;
    hx = fmaxf(hx, NEG_SLOPE * hx);   // leaky-relu, valid since slope < 1
    hy = fmaxf(hy, NEG_SLOPE * hy);
    float c = a2.x * hx + a2.y * hy;
    c += __shfl_xor(c, 1);
    c += __shfl_xor(c, 2);
    c += __shfl_xor(c, 4);
    c += __shfl_xor(c, 8);            // all 16 lanes of the head group hold e_h (log2 domain)
    return c;
}

__device__ __forceinline__ void online_update(float c, float2 xl, float& m, float& z, float& accx, float& accy) {
    if (__any(c > m)) {               // wave-uniform branch; rare after warm-up
        float nm = fmaxf(m, c);
        float s = exp2f(m - nm);
        float w = exp2f(c - nm);
        z = z * s + w;
        accx = accx * s + w * xl.x;
        accy = accy * s + w * xl.y;
        m = nm;
    } else {                          // fast path: no head group raised its max
        float w = exp2f(c - m);
        z += w;
        accx += w * xl.x;
        accy += w * xl.y;
    }
}

__global__ __launch_bounds__(256) void gat_fused_kernel(const float* __restrict__ XL,
    const float* __restrict__ XR, const float* __restrict__ att,
    const int* __restrict__ rowStart, const int* __restrict__ srcS,
    const float* __restrict__ bvec, float* __restrict__ out, int applyElu) {
    int wv = threadIdx.x >> 6;
    int l = threadIdx.x & 63;
    int n = blockIdx.x * 4 + wv;
    if (n >= N_NODES) return;
    int s0 = rowStart[n], s1 = rowStart[n + 1];
    float2 xr2 = *reinterpret_cast<const float2*>(&XR[n * HC + 2 * l]);
    float2 a2  = *reinterpret_cast<const float2*>(&att[2 * l]);
    a2.x *= LOG2E; a2.y *= LOG2E;

    float m = -__builtin_inff();
    float z = 0.f, accx = 0.f, accy = 0.f;

    int p = s0;
    for (; p + 2 <= s1; p += 2) {
        int srcA = srcS[p];
        int srcB = srcS[p + 1];
        float2 xlA = *reinterpret_cast<const float2*>(&XL[srcA * HC + 2 * l]);
        float2 xlB = *reinterpret_cast<const float2*>(&XL[srcB * HC + 2 * l]);
        float cA = edge_score(xlA, xr2, a2);
        float cB = edge_score(xlB, xr2, a2);
        online_update(cA, xlA, m, z, accx, accy);
        online_update(cB, xlB, m, z, accx, accy);
    }
    if (p < s1) {
        int src = srcS[p];
        float2 xl2 = *reinterpret_cast<const float2*>(&XL[src * HC + 2 * l]);
        float c = edge_score(xl2, xr2, a2);
        online_update(c, xl2, m, z, accx, accy);
    }

    float zinv = 1.f / z;
    float2 b2 = *reinterpret_cast<const float2*>(&bvec[2 * l]);
    float ox = accx * zinv + b2.x;
    float oy = accy * zinv + b2.y;
    if (applyElu) {
        ox = ox > 0.f ? ox : (__expf(ox) - 1.f);
        oy = oy > 0.f ? oy : (__expf(oy) - 1.f);
    }
    *reinterpret_cast<float2*>(&out[n * HC + 2 * l]) = make_float2(ox, oy);
}

// ---------------- launch ----------------

extern "C" void kernel_launch(void* const* d_in, const int* in_sizes, int n_in,
                              void* d_out, int out_size, void* d_ws, size_t ws_size,
                              hipStream_t stream) {
    const float* x = (const float*)d_in[0];
    const int* ei = (const int*)d_in[1];
    const int* srcArr = ei;
    const int* dstArr = ei + N_EDGES;

    char* ws = (char*)d_ws;
    size_t off = 0;
    auto alloc = [&](size_t bytes) -> void* {
        void* p = ws + off;
        off = (off + bytes + 511) & ~(size_t)511;
        return p;
    };
    float* P       = (float*)alloc((size_t)N_NODES * HC * 4);
    float* XL      = (float*)alloc((size_t)N_NODES * HC * 4);
    float* XR      = (float*)alloc((size_t)N_NODES * HC * 4);
    int* deg       = (int*)alloc((size_t)N_NODES * 4);
    int* rowStart  = (int*)alloc((size_t)(N_NODES + 1) * 4);
    int* blockSum  = (int*)alloc(64 * 4);
    int* blockOff  = (int*)alloc(64 * 4);
    int* bucketCur = (int*)alloc((size_t)NBUCKETS * 4);
    int2* E2       = (int2*)alloc((size_t)ETOT * 8);
    int* srcS      = (int*)alloc((size_t)ETOT * 4);

    const int NSCAN = (N_NODES + 1023) / 1024;   // 49

    hipMemsetAsync(deg, 0, (size_t)N_NODES * 4, stream);
    hist_kernel<<<(ETOT + 255) / 256, 256, 0, stream>>>(dstArr, deg);
    scanA_kernel<<<NSCAN, 1024, 0, stream>>>(deg, rowStart, blockSum);
    scanB_kernel<<<1, 64, 0, stream>>>(blockSum, blockOff, NSCAN);
    scanC_kernel<<<NSCAN, 1024, 0, stream>>>(rowStart, blockOff);
    init_cursor_kernel<<<(NBUCKETS + 255) / 256, 256, 0, stream>>>(rowStart, bucketCur);
    bucket_scatter_kernel<<<(ETOT + 255) / 256, 256, 0, stream>>>(srcArr, dstArr, bucketCur, E2);
    csr_scatter_kernel<<<NBUCKETS, 256, 0, stream>>>(E2, rowStart, srcS);

    for (int lyr = 0; lyr < 3; lyr++) {
        const float* xin = (lyr == 0) ? x : P;
        float* xout = (lyr == 2) ? (float*)d_out : P;
        const float* Wl  = (const float*)d_in[2 + 6 * lyr + 0];
        const float* bl  = (const float*)d_in[2 + 6 * lyr + 1];
        const float* Wr  = (const float*)d_in[2 + 6 * lyr + 2];
        const float* br  = (const float*)d_in[2 + 6 * lyr + 3];
        const float* att = (const float*)d_in[2 + 6 * lyr + 4];
        const float* bb  = (const float*)d_in[2 + 6 * lyr + 5];

        dim3 ggrid((N_NODES + 63) / 64, 4);
        gemm_kernel<<<ggrid, 256, 0, stream>>>(xin, Wl, bl, Wr, br, XL, XR);

        int nb = (N_NODES + 3) / 4;
        gat_fused_kernel<<<nb, 256, 0, stream>>>(XL, XR, att, rowStart, srcS, bb, xout, lyr < 2 ? 1 : 0);
    }
}

// Round 4
// 634.043 us; speedup vs baseline: 1.4472x; 1.4472x over previous
//
#include <hip/hip_runtime.h>
#include <math.h>

#define N_NODES 50000
#define N_EDGES 1600000
#define ETOT (N_EDGES + N_NODES)
#define HC 128
#define HEADS 4
#define HID 32
#define NEG_SLOPE 0.2f
#define NPB 32                               // nodes per bucket (aligned)
#define NBUCKETS ((N_NODES + NPB - 1) / NPB) // 1563
#define CHUNK 8192
#define NCHUNK ((ETOT + CHUNK - 1) / CHUNK)  // 202
#define LOG2E 1.4426950408889634f

// ---------------- CSR build ----------------

__global__ __launch_bounds__(256) void hist_kernel(const int* __restrict__ dstArr, int* __restrict__ deg) {
    int i = blockIdx.x * 256 + threadIdx.x;
    if (i >= ETOT) return;
    int d = (i < N_EDGES) ? dstArr[i] : (i - N_EDGES);
    atomicAdd(&deg[d], 1);
}

__global__ __launch_bounds__(1024) void scanA_kernel(const int* __restrict__ deg,
                                                     int* __restrict__ rowStart, int* __restrict__ blockSum) {
    __shared__ int buf[1024];
    int i = blockIdx.x * 1024 + threadIdx.x;
    int v = (i < N_NODES) ? deg[i] : 0;
    buf[threadIdx.x] = v;
    __syncthreads();
    for (int off = 1; off < 1024; off <<= 1) {
        int t = (threadIdx.x >= off) ? buf[threadIdx.x - off] : 0;
        __syncthreads();
        buf[threadIdx.x] += t;
        __syncthreads();
    }
    if (i < N_NODES) rowStart[i] = buf[threadIdx.x] - v;   // exclusive, pre-offset
    if (threadIdx.x == 1023) blockSum[blockIdx.x] = buf[1023];
}

__global__ void scanB_kernel(const int* __restrict__ blockSum, int* __restrict__ blockOff, int nb) {
    if (threadIdx.x == 0 && blockIdx.x == 0) {
        int acc = 0;
        for (int j = 0; j < nb; j++) { blockOff[j] = acc; acc += blockSum[j]; }
    }
}

__global__ __launch_bounds__(1024) void scanC_kernel(int* __restrict__ rowStart, const int* __restrict__ blockOff) {
    int i = blockIdx.x * 1024 + threadIdx.x;
    if (i < N_NODES) rowStart[i] += blockOff[blockIdx.x];
    if (i == 0) rowStart[N_NODES] = ETOT;   // sentinel
}

__global__ __launch_bounds__(256) void init_cursor_kernel(const int* __restrict__ rowStart, int* __restrict__ bucketCursor) {
    int b = blockIdx.x * 256 + threadIdx.x;
    if (b < NBUCKETS) bucketCursor[b] = rowStart[b * NPB];
}

// Pass 1: chunked counting-sort scatter to bucket granularity.
// One global atomic per (block,bucket) — not per edge. Edges stashed in regs,
// packed src|(dlocal<<16) (src < 2^16). Scatter via LDS cursors.
__global__ __launch_bounds__(256) void chunk_scatter_kernel(const int* __restrict__ srcArr, const int* __restrict__ dstArr,
                                                            int* __restrict__ bucketCursor, int* __restrict__ E) {
    __shared__ int hist[NBUCKETS];   // then reused as running cursor
    int c0 = blockIdx.x * CHUNK;
    int c1 = min(c0 + CHUNK, ETOT);
    for (int b = threadIdx.x; b < NBUCKETS; b += 256) hist[b] = 0;
    __syncthreads();

    int myP[CHUNK / 256];   // packed src | (d&31)<<16
    int myB[CHUNK / 256];   // bucket id
    int cnt = 0;
    for (int i = c0 + threadIdx.x; i < c1; i += 256) {
        int s, d;
        if (i < N_EDGES) { s = srcArr[i]; d = dstArr[i]; }
        else             { s = i - N_EDGES; d = s; }
        myP[cnt] = s | ((d & (NPB - 1)) << 16);
        myB[cnt] = d >> 5;
        cnt++;
        atomicAdd(&hist[d >> 5], 1);
    }
    __syncthreads();
    // reserve a contiguous range per non-empty bucket; hist[b] becomes cursor
    for (int b = threadIdx.x; b < NBUCKETS; b += 256) {
        int h = hist[b];
        hist[b] = (h > 0) ? atomicAdd(&bucketCursor[b], h) : 0;
    }
    __syncthreads();
    for (int k = 0; k < cnt; k++) {
        int pos = atomicAdd(&hist[myB[k]], 1);
        E[pos] = myP[k];
    }
}

// Pass 2: one block per bucket, LDS cursors, sequential E reads, windowed srcS writes
__global__ __launch_bounds__(256) void csr_scatter_kernel(const int* __restrict__ E, const int* __restrict__ rowStart,
                                                          int* __restrict__ srcS) {
    __shared__ int lcur[NPB];
    int b = blockIdx.x;
    int n0 = b * NPB;
    int nend = min(n0 + NPB, N_NODES);
    if (threadIdx.x < nend - n0) lcur[threadIdx.x] = rowStart[n0 + threadIdx.x];
    __syncthreads();
    int e0 = rowStart[n0];
    int e1 = rowStart[nend];
    for (int i = e0 + threadIdx.x; i < e1; i += 256) {
        int pe = E[i];
        int pos = atomicAdd(&lcur[pe >> 16], 1);
        srcS[pos] = pe & 0xFFFF;
    }
}

// ---------------- GEMM: XL = x@Wl + bl, XR = x@Wr + br ----------------

__global__ __launch_bounds__(256) void gemm_kernel(const float* __restrict__ x,
    const float* __restrict__ Wl, const float* __restrict__ bl,
    const float* __restrict__ Wr, const float* __restrict__ br,
    float* __restrict__ XL, float* __restrict__ XR) {
    __shared__ float As[64][68];
    __shared__ float Bs[64][64];
    int t = threadIdx.x;
    int rb = blockIdx.x * 64;
    int cb = blockIdx.y * 64;
    const float* W; const float* bias; float* out; int c0;
    if (cb < HC) { W = Wl; bias = bl; out = XL; c0 = cb; }
    else         { W = Wr; bias = br; out = XR; c0 = cb - HC; }
    int tx = t & 15, ty = t >> 4;
    float acc[4][4];
#pragma unroll
    for (int i = 0; i < 4; i++)
#pragma unroll
        for (int j = 0; j < 4; j++) acc[i][j] = 0.f;

    for (int kt = 0; kt < 2; kt++) {
#pragma unroll
        for (int it = 0; it < 4; it++) {
            int idx = it * 256 + t;
            int r = idx >> 4, f = idx & 15;
            int gr = rb + r;
            float4 v = make_float4(0.f, 0.f, 0.f, 0.f);
            if (gr < N_NODES) v = *reinterpret_cast<const float4*>(&x[gr * HC + kt * 64 + f * 4]);
            *reinterpret_cast<float4*>(&As[r][f * 4]) = v;
        }
#pragma unroll
        for (int it = 0; it < 4; it++) {
            int idx = it * 256 + t;
            int k = idx >> 4, f = idx & 15;
            float4 v = *reinterpret_cast<const float4*>(&W[(kt * 64 + k) * HC + c0 + f * 4]);
            *reinterpret_cast<float4*>(&Bs[k][f * 4]) = v;
        }
        __syncthreads();
#pragma unroll
        for (int k = 0; k < 64; k++) {
            float a0 = As[ty * 4 + 0][k];
            float a1 = As[ty * 4 + 1][k];
            float a2 = As[ty * 4 + 2][k];
            float a3 = As[ty * 4 + 3][k];
            float4 bv = *reinterpret_cast<const float4*>(&Bs[k][tx * 4]);
            acc[0][0] += a0 * bv.x; acc[0][1] += a0 * bv.y; acc[0][2] += a0 * bv.z; acc[0][3] += a0 * bv.w;
            acc[1][0] += a1 * bv.x; acc[1][1] += a1 * bv.y; acc[1][2] += a1 * bv.z; acc[1][3] += a1 * bv.w;
            acc[2][0] += a2 * bv.x; acc[2][1] += a2 * bv.y; acc[2][2] += a2 * bv.z; acc[2][3] += a2 * bv.w;
            acc[3][0] += a3 * bv.x; acc[3][1] += a3 * bv.y; acc[3][2] += a3 * bv.z; acc[3][3] += a3 * bv.w;
        }
        __syncthreads();
    }
    float4 bb = *reinterpret_cast<const float4*>(&bias[c0 + tx * 4]);
#pragma unroll
    for (int i = 0; i < 4; i++) {
        int gr = rb + ty * 4 + i;
        if (gr < N_NODES) {
            float4 o;
            o.x = acc[i][0] + bb.x; o.y = acc[i][1] + bb.y;
            o.z = acc[i][2] + bb.z; o.w = acc[i][3] + bb.w;
            *reinterpret_cast<float4*>(&out[gr * HC + c0 + tx * 4]) = o;
        }
    }
}

// ---------------- Fused GAT: online softmax + weighted aggregate ----------------

__device__ __forceinline__ float edge_score(float2 xl2, float2 xr2, float2 a2) {
    float hx = xl2.x + xr2.x;
    float hy = xl2.y + xr2.y;
    hx = fmaxf(hx, NEG_SLOPE * hx);
    hy = fmaxf(hy, NEG_SLOPE * hy);
    float c = a2.x * hx + a2.y * hy;
    c += __shfl_xor(c, 1);
    c += __shfl_xor(c, 2);
    c += __shfl_xor(c, 4);
    c += __shfl_xor(c, 8);            // all 16 lanes of the head group hold e_h (log2 domain)
    return c;
}

__device__ __forceinline__ void online_update(float c, float2 xl, float& m, float& z, float& accx, float& accy) {
    if (__any(c > m)) {
        float nm = fmaxf(m, c);
        float s = exp2f(m - nm);
        float w = exp2f(c - nm);
        z = z * s + w;
        accx = accx * s + w * xl.x;
        accy = accy * s + w * xl.y;
        m = nm;
    } else {
        float w = exp2f(c - m);
        z += w;
        accx += w * xl.x;
        accy += w * xl.y;
    }
}

__global__ __launch_bounds__(256) void gat_fused_kernel(const float* __restrict__ XL,
    const float* __restrict__ XR, const float* __restrict__ att,
    const int* __restrict__ rowStart, const int* __restrict__ srcS,
    const float* __restrict__ bvec, float* __restrict__ out, int applyElu) {
    int wv = threadIdx.x >> 6;
    int l = threadIdx.x & 63;
    int n = blockIdx.x * 4 + wv;
    if (n >= N_NODES) return;
    int s0 = rowStart[n], s1 = rowStart[n + 1];
    float2 xr2 = *reinterpret_cast<const float2*>(&XR[n * HC + 2 * l]);
    float2 a2  = *reinterpret_cast<const float2*>(&att[2 * l]);
    a2.x *= LOG2E; a2.y *= LOG2E;

    float m = -__builtin_inff();
    float z = 0.f, accx = 0.f, accy = 0.f;

    int p = s0;
    for (; p + 4 <= s1; p += 4) {
        // 4 independent load chains in flight before the dependent updates
        int srcA = srcS[p];
        int srcB = srcS[p + 1];
        int srcC = srcS[p + 2];
        int srcD = srcS[p + 3];
        float2 xlA = *reinterpret_cast<const float2*>(&XL[srcA * HC + 2 * l]);
        float2 xlB = *reinterpret_cast<const float2*>(&XL[srcB * HC + 2 * l]);
        float2 xlC = *reinterpret_cast<const float2*>(&XL[srcC * HC + 2 * l]);
        float2 xlD = *reinterpret_cast<const float2*>(&XL[srcD * HC + 2 * l]);
        float cA = edge_score(xlA, xr2, a2);
        float cB = edge_score(xlB, xr2, a2);
        float cC = edge_score(xlC, xr2, a2);
        float cD = edge_score(xlD, xr2, a2);
        online_update(cA, xlA, m, z, accx, accy);
        online_update(cB, xlB, m, z, accx, accy);
        online_update(cC, xlC, m, z, accx, accy);
        online_update(cD, xlD, m, z, accx, accy);
    }
    for (; p < s1; p++) {
        int src = srcS[p];
        float2 xl2 = *reinterpret_cast<const float2*>(&XL[src * HC + 2 * l]);
        float c = edge_score(xl2, xr2, a2);
        online_update(c, xl2, m, z, accx, accy);
    }

    float zinv = 1.f / z;
    float2 b2 = *reinterpret_cast<const float2*>(&bvec[2 * l]);
    float ox = accx * zinv + b2.x;
    float oy = accy * zinv + b2.y;
    if (applyElu) {
        ox = ox > 0.f ? ox : (__expf(ox) - 1.f);
        oy = oy > 0.f ? oy : (__expf(oy) - 1.f);
    }
    *reinterpret_cast<float2*>(&out[n * HC + 2 * l]) = make_float2(ox, oy);
}

// ---------------- launch ----------------

extern "C" void kernel_launch(void* const* d_in, const int* in_sizes, int n_in,
                              void* d_out, int out_size, void* d_ws, size_t ws_size,
                              hipStream_t stream) {
    const float* x = (const float*)d_in[0];
    const int* ei = (const int*)d_in[1];
    const int* srcArr = ei;
    const int* dstArr = ei + N_EDGES;

    char* ws = (char*)d_ws;
    size_t off = 0;
    auto alloc = [&](size_t bytes) -> void* {
        void* p = ws + off;
        off = (off + bytes + 511) & ~(size_t)511;
        return p;
    };
    float* P       = (float*)alloc((size_t)N_NODES * HC * 4);
    float* XL      = (float*)alloc((size_t)N_NODES * HC * 4);
    float* XR      = (float*)alloc((size_t)N_NODES * HC * 4);
    int* deg       = (int*)alloc((size_t)N_NODES * 4);
    int* rowStart  = (int*)alloc((size_t)(N_NODES + 1) * 4);
    int* blockSum  = (int*)alloc(64 * 4);
    int* blockOff  = (int*)alloc(64 * 4);
    int* bucketCur = (int*)alloc((size_t)NBUCKETS * 4);
    int* E         = (int*)alloc((size_t)ETOT * 4);
    int* srcS      = (int*)alloc((size_t)ETOT * 4);

    const int NSCAN = (N_NODES + 1023) / 1024;   // 49

    hipMemsetAsync(deg, 0, (size_t)N_NODES * 4, stream);
    hist_kernel<<<(ETOT + 255) / 256, 256, 0, stream>>>(dstArr, deg);
    scanA_kernel<<<NSCAN, 1024, 0, stream>>>(deg, rowStart, blockSum);
    scanB_kernel<<<1, 64, 0, stream>>>(blockSum, blockOff, NSCAN);
    scanC_kernel<<<NSCAN, 1024, 0, stream>>>(rowStart, blockOff);
    init_cursor_kernel<<<(NBUCKETS + 255) / 256, 256, 0, stream>>>(rowStart, bucketCur);
    chunk_scatter_kernel<<<NCHUNK, 256, 0, stream>>>(srcArr, dstArr, bucketCur, E);
    csr_scatter_kernel<<<NBUCKETS, 256, 0, stream>>>(E, rowStart, srcS);

    for (int lyr = 0; lyr < 3; lyr++) {
        const float* xin = (lyr == 0) ? x : P;
        float* xout = (lyr == 2) ? (float*)d_out : P;
        const float* Wl  = (const float*)d_in[2 + 6 * lyr + 0];
        const float* bl  = (const float*)d_in[2 + 6 * lyr + 1];
        const float* Wr  = (const float*)d_in[2 + 6 * lyr + 2];
        const float* br  = (const float*)d_in[2 + 6 * lyr + 3];
        const float* att = (const float*)d_in[2 + 6 * lyr + 4];
        const float* bb  = (const float*)d_in[2 + 6 * lyr + 5];

        dim3 ggrid((N_NODES + 63) / 64, 4);
        gemm_kernel<<<ggrid, 256, 0, stream>>>(xin, Wl, bl, Wr, br, XL, XR);

        int nb = (N_NODES + 3) / 4;
        gat_fused_kernel<<<nb, 256, 0, stream>>>(XL, XR, att, rowStart, srcS, bb, xout, lyr < 2 ? 1 : 0);
    }
}